// Round 1
// baseline (232.168 us; speedup 1.0000x reference)
//
#include <hip/hip_runtime.h>
#include <math.h>

#define NN 10000
#define NE 320000
#define IN_DIM 512
#define FEAT_DIM 128
#define OD 64
#define NH 8
#define ZD 512          // OD*NH
#define NEG 0.01f

// ---------- prep: wfa[f][h] = sum_d w_feat[f][h*64+d] * a_feat[d] ----------
__global__ void k_wfa(const float* __restrict__ w_feat, const float* __restrict__ w_attn,
                      float* __restrict__ wfa) {
  int tid = blockIdx.x * 256 + threadIdx.x;
  if (tid >= FEAT_DIM * NH) return;
  int f = tid >> 3, h = tid & 7;
  const float* wr = w_feat + (size_t)f * ZD + h * OD;
  const float* a  = w_attn + 2 * OD;
  float s = 0.f;
  #pragma unroll 8
  for (int d = 0; d < OD; ++d) s += wr[d] * a[d];
  wfa[f * NH + h] = s;
}

// ---------- CSR row offsets via lower_bound on sorted dst ----------
__global__ void k_rows(const int* __restrict__ dst, int* __restrict__ row_start) {
  int n = blockIdx.x * 256 + threadIdx.x;
  if (n > NN) return;
  int lo = 0, hi = NE;
  while (lo < hi) { int mid = (lo + hi) >> 1; if (dst[mid] < n) lo = mid + 1; else hi = mid; }
  row_start[n] = lo;
}

// ---------- z = h @ w_fc  (fp32 tiled GEMM, 128x64 tile) ----------
#define BM 128
#define BN 64
#define BK 16
__global__ __launch_bounds__(256) void k_gemm(const float* __restrict__ A,
                                              const float* __restrict__ B,
                                              float* __restrict__ Z) {
  __shared__ float As[BK][BM + 4];   // stored transposed: As[k][m]
  __shared__ float Bs[BK][BN];
  const int t  = threadIdx.x;
  const int m0 = blockIdx.x * BM;
  const int n0 = blockIdx.y * BN;
  const int ty = t >> 4, tx = t & 15;      // compute: 16x16 groups, micro 8x4
  const int lr = t >> 2;                   // A loader: 4 threads/row
  const int lk = (t & 3) * 4;
  const int br = t >> 4;                   // B loader: 16 threads/row
  const int bc = (t & 15) * 4;

  float acc[8][4];
  #pragma unroll
  for (int i = 0; i < 8; i++)
    #pragma unroll
    for (int j = 0; j < 4; j++) acc[i][j] = 0.f;

  for (int k0 = 0; k0 < IN_DIM; k0 += BK) {
    #pragma unroll
    for (int p = 0; p < 2; p++) {
      int r  = lr + p * 64;
      int gm = m0 + r;
      float4 v = make_float4(0.f, 0.f, 0.f, 0.f);
      if (gm < NN) v = *(const float4*)(A + (size_t)gm * IN_DIM + k0 + lk);
      As[lk + 0][r] = v.x; As[lk + 1][r] = v.y; As[lk + 2][r] = v.z; As[lk + 3][r] = v.w;
    }
    *(float4*)&Bs[br][bc] = *(const float4*)(B + (size_t)(k0 + br) * ZD + n0 + bc);
    __syncthreads();
    #pragma unroll
    for (int k = 0; k < BK; k++) {
      float a[8], b[4];
      *(float4*)&a[0] = *(float4*)&As[k][ty * 8];
      *(float4*)&a[4] = *(float4*)&As[k][ty * 8 + 4];
      *(float4*)&b[0] = *(float4*)&Bs[k][tx * 4];
      #pragma unroll
      for (int i = 0; i < 8; i++)
        #pragma unroll
        for (int j = 0; j < 4; j++)
          acc[i][j] = fmaf(a[i], b[j], acc[i][j]);
    }
    __syncthreads();
  }
  #pragma unroll
  for (int i = 0; i < 8; i++) {
    int gm = m0 + ty * 8 + i;
    if (gm < NN) *(float4*)(Z + (size_t)gm * ZD + n0 + tx * 4) = *(float4*)&acc[i][0];
  }
}

// ---------- per-node attention scores from z ----------
__global__ void k_scores(const float* __restrict__ Z, const float* __restrict__ w_attn,
                         float* __restrict__ s_src, float* __restrict__ s_dst) {
  int tid = blockIdx.x * 256 + threadIdx.x;
  if (tid >= NN * NH) return;
  int n = tid >> 3, h = tid & 7;
  const float* zr = Z + (size_t)n * ZD + h * OD;
  float a1 = 0.f, a2 = 0.f;
  #pragma unroll
  for (int i = 0; i < OD; i += 4) {
    float4 zv = *(const float4*)(zr + i);
    float4 as = *(const float4*)(w_attn + i);
    float4 ad = *(const float4*)(w_attn + OD + i);
    a1 += zv.x * as.x + zv.y * as.y + zv.z * as.z + zv.w * as.w;
    a2 += zv.x * ad.x + zv.y * ad.y + zv.z * ad.z + zv.w * ad.w;
  }
  s_src[tid] = a1;
  s_dst[tid] = a2;
}

// ---------- per-edge scores: e = lrelu(s_src[src] + s_dst[dst] + dep_emb@wfa) ----------
__global__ __launch_bounds__(256) void k_edge(const float* __restrict__ dep_emb,
    const int* __restrict__ src, const int* __restrict__ dst,
    const float* __restrict__ wfa, const float* __restrict__ s_src,
    const float* __restrict__ s_dst, float* __restrict__ e_out) {
  __shared__ float rows[64][FEAT_DIM + 4];
  __shared__ float wfa_s[FEAT_DIM * NH];
  const int t  = threadIdx.x;
  const int e0 = blockIdx.x * 64;
  *(float4*)&wfa_s[t * 4] = *(const float4*)&wfa[t * 4];
  const float4* g = (const float4*)(dep_emb + (size_t)e0 * FEAT_DIM);
  #pragma unroll
  for (int r = 0; r < 8; r++) {
    int idx = t + r * 256;
    float4 v = g[idx];
    *(float4*)&rows[idx >> 5][(idx & 31) * 4] = v;
  }
  __syncthreads();
  const int le = t >> 2, c = t & 3;
  float acc[NH];
  #pragma unroll
  for (int h = 0; h < NH; h++) acc[h] = 0.f;
  #pragma unroll
  for (int i = 0; i < 32; i += 4) {
    float4 v = *(float4*)&rows[le][c * 32 + i];
    const float* w0 = &wfa_s[(c * 32 + i) * NH];
    #pragma unroll
    for (int j = 0; j < 4; j++) {
      float x = (&v.x)[j];
      #pragma unroll
      for (int h = 0; h < NH; h++) acc[h] = fmaf(x, w0[j * NH + h], acc[h]);
    }
  }
  #pragma unroll
  for (int h = 0; h < NH; h++) {
    acc[h] += __shfl_xor(acc[h], 1);
    acc[h] += __shfl_xor(acc[h], 2);
  }
  int eid = e0 + le;
  int s = src[eid], dd = dst[eid];
  int h0 = c * 2;
  float v0 = acc[h0]     + s_src[s * NH + h0]     + s_dst[dd * NH + h0];
  float v1 = acc[h0 + 1] + s_src[s * NH + h0 + 1] + s_dst[dd * NH + h0 + 1];
  float2 r2;
  r2.x = v0 >= 0.f ? v0 : NEG * v0;
  r2.y = v1 >= 0.f ? v1 : NEG * v1;
  *(float2*)&e_out[(size_t)eid * NH + h0] = r2;
}

// ---------- segment softmax + weighted scatter-gather aggregate ----------
#define CHUNK 512
__global__ __launch_bounds__(512) void k_agg(const float* __restrict__ e_sc,
    const int* __restrict__ src, const int* __restrict__ row_start,
    const float* __restrict__ Z, float* __restrict__ out) {
  const int n = blockIdx.x;
  const int start = row_start[n], end = row_start[n + 1];
  const int t = threadIdx.x;
  const int h = t >> 6;        // wave index == head
  const int lane = t & 63;
  __shared__ float m_s[NH], den_s[NH];
  __shared__ float ex_s[CHUNK * NH];
  __shared__ int   src_s[CHUNK];

  // pass 1: per-head max + denom (wave per head)
  {
    float mx = -INFINITY;
    for (int eid = start + lane; eid < end; eid += 64)
      mx = fmaxf(mx, e_sc[(size_t)eid * NH + h]);
    #pragma unroll
    for (int o = 32; o > 0; o >>= 1) mx = fmaxf(mx, __shfl_xor(mx, o));
    float sm = 0.f;
    for (int eid = start + lane; eid < end; eid += 64)
      sm += __expf(e_sc[(size_t)eid * NH + h] - mx);
    #pragma unroll
    for (int o = 32; o > 0; o >>= 1) sm += __shfl_xor(sm, o);
    if (lane == 0) { m_s[h] = (end > start) ? mx : 0.f; den_s[h] = (end > start) ? sm : 0.f; }
  }
  __syncthreads();

  // pass 2: chunked exp staging + coalesced z-gather accumulate
  float acc = 0.f;
  for (int c0 = start; c0 < end; c0 += CHUNK) {
    int cn = min(CHUNK, end - c0);
    for (int idx = t; idx < cn * NH; idx += 512) {
      int i = idx >> 3, hh = idx & 7;
      ex_s[idx] = __expf(e_sc[(size_t)(c0 + i) * NH + hh] - m_s[hh]);
    }
    for (int idx = t; idx < cn; idx += 512) src_s[idx] = src[c0 + idx];
    __syncthreads();
    for (int i = 0; i < cn; i++)
      acc = fmaf(ex_s[i * NH + h], Z[(size_t)src_s[i] * ZD + t], acc);
    __syncthreads();
  }
  float den = den_s[h];
  out[(size_t)n * ZD + t] = (den > 0.f) ? acc / den : 0.f;
}

extern "C" void kernel_launch(void* const* d_in, const int* in_sizes, int n_in,
                              void* d_out, int out_size, void* d_ws, size_t ws_size,
                              hipStream_t stream) {
  const float* h      = (const float*)d_in[0];
  const float* dep    = (const float*)d_in[1];
  const int*   src    = (const int*)d_in[2];
  const int*   dst    = (const int*)d_in[3];
  const float* w_fc   = (const float*)d_in[4];
  const float* w_feat = (const float*)d_in[5];
  const float* w_attn = (const float*)d_in[6];
  float* out = (float*)d_out;

  float* z      = (float*)d_ws;                       // N*512
  float* s_src  = z + (size_t)NN * ZD;                // N*8
  float* s_dst  = s_src + NN * NH;                    // N*8
  float* e_sc   = s_dst + NN * NH;                    // E*8
  float* wfa    = e_sc + (size_t)NE * NH;             // 128*8
  int*   row_st = (int*)(wfa + FEAT_DIM * NH);        // N+1

  k_gemm  <<<dim3((NN + BM - 1) / BM, ZD / BN), 256, 0, stream>>>(h, w_fc, z);
  k_wfa   <<<(FEAT_DIM * NH + 255) / 256, 256, 0, stream>>>(w_feat, w_attn, wfa);
  k_rows  <<<(NN + 1 + 255) / 256, 256, 0, stream>>>(dst, row_st);
  k_scores<<<(NN * NH + 255) / 256, 256, 0, stream>>>(z, w_attn, s_src, s_dst);
  k_edge  <<<NE / 64, 256, 0, stream>>>(dep, src, dst, wfa, s_src, s_dst, e_sc);
  k_agg   <<<NN, 512, 0, stream>>>(e_sc, src, row_st, z, out);
}

// Round 2
// 183.183 us; speedup vs baseline: 1.2674x; 1.2674x over previous
//
#include <hip/hip_runtime.h>
#include <math.h>

#define NN 10000
#define NPAD 10112     // 79*128
#define NE 320000
#define IN_DIM 512
#define FEAT_DIM 128
#define OD 64
#define NH 8
#define ZD 512          // OD*NH
#define NEG 0.01f

typedef __attribute__((ext_vector_type(8))) __bf16 bf16x8;
typedef __attribute__((ext_vector_type(4))) float f32x4;

__device__ __forceinline__ unsigned short f2b(float f) {
  __bf16 b = (__bf16)f;
  return __builtin_bit_cast(unsigned short, b);
}

__device__ __forceinline__ void gload16(const void* g, void* l) {
  __builtin_amdgcn_global_load_lds((const __attribute__((address_space(1))) unsigned int*)g,
                                   (__attribute__((address_space(3))) unsigned int*)l, 16, 0, 0);
}

// ---------- convert h (fp32 [NN][512]) -> hb (bf16 [NPAD][512], zero-padded) ----------
__global__ __launch_bounds__(256) void k_h2b(const float* __restrict__ h, unsigned short* __restrict__ hb) {
  size_t tid = (size_t)blockIdx.x * 256 + threadIdx.x;
  size_t base = tid * 8;
  if (base >= (size_t)NPAD * IN_DIM) return;
  int row = (int)(base >> 9);
  ushort4 o0, o1;
  if (row < NN) {
    float4 v0 = *(const float4*)(h + base);
    float4 v1 = *(const float4*)(h + base + 4);
    o0 = make_ushort4(f2b(v0.x), f2b(v0.y), f2b(v0.z), f2b(v0.w));
    o1 = make_ushort4(f2b(v1.x), f2b(v1.y), f2b(v1.z), f2b(v1.w));
  } else {
    o0 = make_ushort4(0, 0, 0, 0);
    o1 = make_ushort4(0, 0, 0, 0);
  }
  *(ushort4*)(hb + base) = o0;
  *(ushort4*)(hb + base + 4) = o1;
}

// ---------- transpose+convert w_fc (fp32 [K=512][N=512]) -> wt (bf16 [N][K]) ----------
__global__ __launch_bounds__(256) void k_wt(const float* __restrict__ w, unsigned short* __restrict__ wt) {
  __shared__ float tile[32][33];
  const int tx = (blockIdx.x & 15) * 32;   // col tile (N dim of w)
  const int ty = (blockIdx.x >> 4) * 32;   // row tile (K dim of w)
  const int t = threadIdx.x;
  const int r = t >> 3, c4 = (t & 7) * 4;
  float4 v = *(const float4*)(w + (size_t)(ty + r) * ZD + tx + c4);
  tile[r][c4 + 0] = v.x; tile[r][c4 + 1] = v.y; tile[r][c4 + 2] = v.z; tile[r][c4 + 3] = v.w;
  __syncthreads();
  // wt[tx + r][ty + c4 .. +4] = tile[c4..][r]
  ushort4 o = make_ushort4(f2b(tile[c4 + 0][r]), f2b(tile[c4 + 1][r]),
                           f2b(tile[c4 + 2][r]), f2b(tile[c4 + 3][r]));
  *(ushort4*)(wt + (size_t)(tx + r) * IN_DIM + ty + c4) = o;
}

// ---------- z = hb @ wt^T  (bf16 MFMA, 128x128 tile, BK=32, m97 structure) ----------
__global__ __launch_bounds__(256) void k_gemm_bf(const unsigned short* __restrict__ A,   // [NPAD][512] bf16
                                                 const unsigned short* __restrict__ Bt,  // [512][512] bf16 (N-major)
                                                 float* __restrict__ Z) {
  // LDS layout [kq][row][8] : conflict-free ds_read_b128, linear for global_load_lds
  __shared__ unsigned short As[4 * 128 * 8];
  __shared__ unsigned short Bs[4 * 128 * 8];
  const int t = threadIdx.x;
  const int m0 = blockIdx.x * 128;
  const int n0 = blockIdx.y * 128;
  const int lane = t & 63, wave = t >> 6;
  const int wr = (wave >> 1) * 64, wc = (wave & 1) * 64;
  const int fr = lane & 15, kq = lane >> 4;

  f32x4 acc[4][4] = {};

  const int idx0 = t, idx1 = t + 256;
  const unsigned short* ga0 = A + (size_t)(m0 + (idx0 & 127)) * IN_DIM + (idx0 >> 7) * 8;
  const unsigned short* ga1 = A + (size_t)(m0 + (idx1 & 127)) * IN_DIM + (idx1 >> 7) * 8;
  const unsigned short* gb0 = Bt + (size_t)(n0 + (idx0 & 127)) * IN_DIM + (idx0 >> 7) * 8;
  const unsigned short* gb1 = Bt + (size_t)(n0 + (idx1 & 127)) * IN_DIM + (idx1 >> 7) * 8;
  unsigned short* la0 = &As[idx0 * 8];
  unsigned short* la1 = &As[idx1 * 8];
  unsigned short* lb0 = &Bs[idx0 * 8];
  unsigned short* lb1 = &Bs[idx1 * 8];

  for (int k0 = 0; k0 < IN_DIM; k0 += 32) {
    gload16(ga0 + k0, la0);
    gload16(ga1 + k0, la1);
    gload16(gb0 + k0, lb0);
    gload16(gb1 + k0, lb1);
    __syncthreads();   // drains vmcnt before barrier

    bf16x8 a[4], b[4];
    #pragma unroll
    for (int m = 0; m < 4; m++)
      a[m] = *(const bf16x8*)&As[(kq * 128 + wr + m * 16 + fr) * 8];
    #pragma unroll
    for (int n = 0; n < 4; n++)
      b[n] = *(const bf16x8*)&Bs[(kq * 128 + wc + n * 16 + fr) * 8];
    #pragma unroll
    for (int m = 0; m < 4; m++)
      #pragma unroll
      for (int n = 0; n < 4; n++)
        acc[m][n] = __builtin_amdgcn_mfma_f32_16x16x32_bf16(a[m], b[n], acc[m][n], 0, 0, 0);
    __syncthreads();
  }

  // C layout: col = lane&15, row = (lane>>4)*4 + j   [m89-verified]
  const int crow = (lane >> 4) * 4;
  const int ccol = lane & 15;
  #pragma unroll
  for (int m = 0; m < 4; m++) {
    #pragma unroll
    for (int n = 0; n < 4; n++) {
      int row = m0 + wr + m * 16 + crow;
      int col = n0 + wc + n * 16 + ccol;
      #pragma unroll
      for (int j = 0; j < 4; j++)
        if (row + j < NN) Z[(size_t)(row + j) * ZD + col] = acc[m][n][j];
    }
  }
}

// ---------- prep: wfa[f][h] = sum_d w_feat[f][h*64+d] * a_feat[d] ----------
__global__ void k_wfa(const float* __restrict__ w_feat, const float* __restrict__ w_attn,
                      float* __restrict__ wfa) {
  int tid = blockIdx.x * 256 + threadIdx.x;
  if (tid >= FEAT_DIM * NH) return;
  int f = tid >> 3, h = tid & 7;
  const float* wr = w_feat + (size_t)f * ZD + h * OD;
  const float* a  = w_attn + 2 * OD;
  float s = 0.f;
  #pragma unroll 8
  for (int d = 0; d < OD; ++d) s += wr[d] * a[d];
  wfa[f * NH + h] = s;
}

// ---------- CSR row offsets via lower_bound on sorted dst ----------
__global__ void k_rows(const int* __restrict__ dst, int* __restrict__ row_start) {
  int n = blockIdx.x * 256 + threadIdx.x;
  if (n > NN) return;
  int lo = 0, hi = NE;
  while (lo < hi) { int mid = (lo + hi) >> 1; if (dst[mid] < n) lo = mid + 1; else hi = mid; }
  row_start[n] = lo;
}

// ---------- per-node attention scores from z ----------
__global__ void k_scores(const float* __restrict__ Z, const float* __restrict__ w_attn,
                         float* __restrict__ s_src, float* __restrict__ s_dst) {
  int tid = blockIdx.x * 256 + threadIdx.x;
  if (tid >= NN * NH) return;
  int n = tid >> 3, h = tid & 7;
  const float* zr = Z + (size_t)n * ZD + h * OD;
  float a1 = 0.f, a2 = 0.f;
  #pragma unroll
  for (int i = 0; i < OD; i += 4) {
    float4 zv = *(const float4*)(zr + i);
    float4 as = *(const float4*)(w_attn + i);
    float4 ad = *(const float4*)(w_attn + OD + i);
    a1 += zv.x * as.x + zv.y * as.y + zv.z * as.z + zv.w * as.w;
    a2 += zv.x * ad.x + zv.y * ad.y + zv.z * ad.z + zv.w * ad.w;
  }
  s_src[tid] = a1;
  s_dst[tid] = a2;
}

// ---------- per-edge scores: e = lrelu(s_src[src] + s_dst[dst] + dep_emb@wfa) ----------
__global__ __launch_bounds__(256) void k_edge(const float* __restrict__ dep_emb,
    const int* __restrict__ src, const int* __restrict__ dst,
    const float* __restrict__ wfa, const float* __restrict__ s_src,
    const float* __restrict__ s_dst, float* __restrict__ e_out) {
  __shared__ float rows[64][FEAT_DIM + 4];
  __shared__ float wfa_s[FEAT_DIM * NH];
  const int t  = threadIdx.x;
  const int e0 = blockIdx.x * 64;
  *(float4*)&wfa_s[t * 4] = *(const float4*)&wfa[t * 4];
  const float4* g = (const float4*)(dep_emb + (size_t)e0 * FEAT_DIM);
  #pragma unroll
  for (int r = 0; r < 8; r++) {
    int idx = t + r * 256;
    float4 v = g[idx];
    *(float4*)&rows[idx >> 5][(idx & 31) * 4] = v;
  }
  __syncthreads();
  const int le = t >> 2, c = t & 3;
  float acc[NH];
  #pragma unroll
  for (int h = 0; h < NH; h++) acc[h] = 0.f;
  #pragma unroll
  for (int i = 0; i < 32; i += 4) {
    float4 v = *(float4*)&rows[le][c * 32 + i];
    const float* w0 = &wfa_s[(c * 32 + i) * NH];
    #pragma unroll
    for (int j = 0; j < 4; j++) {
      float x = (&v.x)[j];
      #pragma unroll
      for (int h = 0; h < NH; h++) acc[h] = fmaf(x, w0[j * NH + h], acc[h]);
    }
  }
  #pragma unroll
  for (int h = 0; h < NH; h++) {
    acc[h] += __shfl_xor(acc[h], 1);
    acc[h] += __shfl_xor(acc[h], 2);
  }
  int eid = e0 + le;
  int s = src[eid], dd = dst[eid];
  int h0 = c * 2;
  float v0 = acc[h0]     + s_src[s * NH + h0]     + s_dst[dd * NH + h0];
  float v1 = acc[h0 + 1] + s_src[s * NH + h0 + 1] + s_dst[dd * NH + h0 + 1];
  float2 r2;
  r2.x = v0 >= 0.f ? v0 : NEG * v0;
  r2.y = v1 >= 0.f ? v1 : NEG * v1;
  *(float2*)&e_out[(size_t)eid * NH + h0] = r2;
}

// ---------- segment softmax + weighted scatter-gather aggregate ----------
#define CHUNK 512
__global__ __launch_bounds__(512) void k_agg(const float* __restrict__ e_sc,
    const int* __restrict__ src, const int* __restrict__ row_start,
    const float* __restrict__ Z, float* __restrict__ out) {
  const int n = blockIdx.x;
  const int start = row_start[n], end = row_start[n + 1];
  const int t = threadIdx.x;
  const int h = t >> 6;        // wave index == head
  const int lane = t & 63;
  __shared__ float m_s[NH], den_s[NH];
  __shared__ float ex_s[CHUNK * NH];
  __shared__ int   src_s[CHUNK];

  // pass 1: per-head max + denom (wave per head)
  {
    float mx = -INFINITY;
    for (int eid = start + lane; eid < end; eid += 64)
      mx = fmaxf(mx, e_sc[(size_t)eid * NH + h]);
    #pragma unroll
    for (int o = 32; o > 0; o >>= 1) mx = fmaxf(mx, __shfl_xor(mx, o));
    float sm = 0.f;
    for (int eid = start + lane; eid < end; eid += 64)
      sm += __expf(e_sc[(size_t)eid * NH + h] - mx);
    #pragma unroll
    for (int o = 32; o > 0; o >>= 1) sm += __shfl_xor(sm, o);
    if (lane == 0) { m_s[h] = (end > start) ? mx : 0.f; den_s[h] = (end > start) ? sm : 0.f; }
  }
  __syncthreads();

  // pass 2: chunked exp staging + coalesced z-gather accumulate
  float acc = 0.f;
  for (int c0 = start; c0 < end; c0 += CHUNK) {
    int cn = min(CHUNK, end - c0);
    for (int idx = t; idx < cn * NH; idx += 512) {
      int i = idx >> 3, hh = idx & 7;
      ex_s[idx] = __expf(e_sc[(size_t)(c0 + i) * NH + hh] - m_s[hh]);
    }
    for (int idx = t; idx < cn; idx += 512) src_s[idx] = src[c0 + idx];
    __syncthreads();
    for (int i = 0; i < cn; i++)
      acc = fmaf(ex_s[i * NH + h], Z[(size_t)src_s[i] * ZD + t], acc);
    __syncthreads();
  }
  float den = den_s[h];
  out[(size_t)n * ZD + t] = (den > 0.f) ? acc / den : 0.f;
}

extern "C" void kernel_launch(void* const* d_in, const int* in_sizes, int n_in,
                              void* d_out, int out_size, void* d_ws, size_t ws_size,
                              hipStream_t stream) {
  const float* h      = (const float*)d_in[0];
  const float* dep    = (const float*)d_in[1];
  const int*   src    = (const int*)d_in[2];
  const int*   dst    = (const int*)d_in[3];
  const float* w_fc   = (const float*)d_in[4];
  const float* w_feat = (const float*)d_in[5];
  const float* w_attn = (const float*)d_in[6];
  float* out = (float*)d_out;

  float* z      = (float*)d_ws;                       // NN*512 f32
  float* s_src  = z + (size_t)NN * ZD;                // NN*8
  float* s_dst  = s_src + NN * NH;                    // NN*8
  float* e_sc   = s_dst + NN * NH;                    // NE*8
  float* wfa    = e_sc + (size_t)NE * NH;             // 128*8
  int*   row_st = (int*)(wfa + FEAT_DIM * NH);        // NN+1
  unsigned short* hb = (unsigned short*)(row_st + NN + 2);  // NPAD*512 bf16
  unsigned short* wt = hb + (size_t)NPAD * IN_DIM;          // 512*512 bf16

  k_h2b   <<<(int)(((size_t)NPAD * IN_DIM / 8 + 255) / 256), 256, 0, stream>>>(h, hb);
  k_wt    <<<256, 256, 0, stream>>>(w_fc, wt);
  k_gemm_bf<<<dim3(NPAD / 128, ZD / 128), 256, 0, stream>>>(hb, wt, z);
  k_wfa   <<<(FEAT_DIM * NH + 255) / 256, 256, 0, stream>>>(w_feat, w_attn, wfa);
  k_rows  <<<(NN + 1 + 255) / 256, 256, 0, stream>>>(dst, row_st);
  k_scores<<<(NN * NH + 255) / 256, 256, 0, stream>>>(z, w_attn, s_src, s_dst);
  k_edge  <<<NE / 64, 256, 0, stream>>>(dep, src, dst, wfa, s_src, s_dst, e_sc);
  k_agg   <<<NN, 512, 0, stream>>>(e_sc, src, row_st, z, out);
}

// Round 3
// 128.778 us; speedup vs baseline: 1.8029x; 1.4225x over previous
//
#include <hip/hip_runtime.h>
#include <math.h>

#define NN 10000
#define NPAD 10112     // 79*128
#define NE 320000
#define IN_DIM 512
#define FEAT_DIM 128
#define OD 64
#define NH 8
#define ZD 512          // OD*NH
#define NEG 0.01f

typedef __attribute__((ext_vector_type(8))) __bf16 bf16x8;
typedef __attribute__((ext_vector_type(4))) float f32x4;

__device__ __forceinline__ unsigned short f2b(float f) {
  __bf16 b = (__bf16)f;
  return __builtin_bit_cast(unsigned short, b);
}
__device__ __forceinline__ float b2f(unsigned short u) {
  unsigned int x = ((unsigned int)u) << 16;
  return __builtin_bit_cast(float, x);
}

__device__ __forceinline__ void gload16(const void* g, void* l) {
  __builtin_amdgcn_global_load_lds((const __attribute__((address_space(1))) unsigned int*)g,
                                   (__attribute__((address_space(3))) unsigned int*)l, 16, 0, 0);
}

// ---------- fused prep: h->bf16 | w_fc transpose->bf16 | wfa fold | CSR rows ----------
// blocks [0,2528): h2b   [2528,2784): wt   [2784,2788): wfa   [2788,2828): rows
#define PREP_H2B 2528
#define PREP_WT  (PREP_H2B + 256)
#define PREP_WFA (PREP_WT + 4)
#define PREP_ALL (PREP_WFA + 40)
__global__ __launch_bounds__(256) void k_prep(const float* __restrict__ h,
    const float* __restrict__ w_fc, const float* __restrict__ w_feat,
    const float* __restrict__ w_attn, const int* __restrict__ dst,
    unsigned short* __restrict__ hb, unsigned short* __restrict__ wt,
    float* __restrict__ wfa, int* __restrict__ row_start) {
  const int bid = blockIdx.x, t = threadIdx.x;
  if (bid < PREP_H2B) {
    size_t base = ((size_t)bid * 256 + t) * 8;
    int row = (int)(base >> 9);
    ushort4 o0, o1;
    if (row < NN) {
      float4 v0 = *(const float4*)(h + base);
      float4 v1 = *(const float4*)(h + base + 4);
      o0 = make_ushort4(f2b(v0.x), f2b(v0.y), f2b(v0.z), f2b(v0.w));
      o1 = make_ushort4(f2b(v1.x), f2b(v1.y), f2b(v1.z), f2b(v1.w));
    } else {
      o0 = make_ushort4(0, 0, 0, 0);
      o1 = make_ushort4(0, 0, 0, 0);
    }
    *(ushort4*)(hb + base) = o0;
    *(ushort4*)(hb + base + 4) = o1;
  } else if (bid < PREP_WT) {
    __shared__ float tile[32][33];
    const int b2 = bid - PREP_H2B;
    const int tx = (b2 & 15) * 32, ty = (b2 >> 4) * 32;
    const int r = t >> 3, c4 = (t & 7) * 4;
    float4 v = *(const float4*)(w_fc + (size_t)(ty + r) * ZD + tx + c4);
    tile[r][c4 + 0] = v.x; tile[r][c4 + 1] = v.y; tile[r][c4 + 2] = v.z; tile[r][c4 + 3] = v.w;
    __syncthreads();
    ushort4 o = make_ushort4(f2b(tile[c4 + 0][r]), f2b(tile[c4 + 1][r]),
                             f2b(tile[c4 + 2][r]), f2b(tile[c4 + 3][r]));
    *(ushort4*)(wt + (size_t)(tx + r) * IN_DIM + ty + c4) = o;
  } else if (bid < PREP_WFA) {
    int tid = (bid - PREP_WT) * 256 + t;
    if (tid < FEAT_DIM * NH) {
      int f = tid >> 3, hh = tid & 7;
      const float* wr = w_feat + (size_t)f * ZD + hh * OD;
      const float* a  = w_attn + 2 * OD;
      float s = 0.f;
      #pragma unroll 8
      for (int d = 0; d < OD; ++d) s += wr[d] * a[d];
      wfa[f * NH + hh] = s;
    }
  } else {
    int n = (bid - PREP_WFA) * 256 + t;
    if (n <= NN) {
      int lo = 0, hi = NE;
      while (lo < hi) { int mid = (lo + hi) >> 1; if (dst[mid] < n) lo = mid + 1; else hi = mid; }
      row_start[n] = lo;
    }
  }
}

// ---------- z = hb @ wt^T (bf16 MFMA) + fused node-score epilogue ----------
// writes zb (bf16 [NN][512]) and s_src/s_dst ([NN][8]) directly from fp32 acc
__global__ __launch_bounds__(256) void k_gemm_bf(const unsigned short* __restrict__ A,
                                                 const unsigned short* __restrict__ Bt,
                                                 const float* __restrict__ w_attn,
                                                 unsigned short* __restrict__ zb,
                                                 float* __restrict__ s_src,
                                                 float* __restrict__ s_dst) {
  __shared__ unsigned short As[4 * 128 * 8];
  __shared__ unsigned short Bs[4 * 128 * 8];
  const int t = threadIdx.x;
  const int m0 = blockIdx.x * 128;
  const int n0 = blockIdx.y * 128;
  const int lane = t & 63, wave = t >> 6;
  const int wr = (wave >> 1) * 64, wc = (wave & 1) * 64;
  const int fr = lane & 15, kq = lane >> 4;

  f32x4 acc[4][4] = {};

  const int idx0 = t, idx1 = t + 256;
  const unsigned short* ga0 = A + (size_t)(m0 + (idx0 & 127)) * IN_DIM + (idx0 >> 7) * 8;
  const unsigned short* ga1 = A + (size_t)(m0 + (idx1 & 127)) * IN_DIM + (idx1 >> 7) * 8;
  const unsigned short* gb0 = Bt + (size_t)(n0 + (idx0 & 127)) * IN_DIM + (idx0 >> 7) * 8;
  const unsigned short* gb1 = Bt + (size_t)(n0 + (idx1 & 127)) * IN_DIM + (idx1 >> 7) * 8;
  unsigned short* la0 = &As[idx0 * 8];
  unsigned short* la1 = &As[idx1 * 8];
  unsigned short* lb0 = &Bs[idx0 * 8];
  unsigned short* lb1 = &Bs[idx1 * 8];

  for (int k0 = 0; k0 < IN_DIM; k0 += 32) {
    gload16(ga0 + k0, la0);
    gload16(ga1 + k0, la1);
    gload16(gb0 + k0, lb0);
    gload16(gb1 + k0, lb1);
    __syncthreads();

    bf16x8 a[4], b[4];
    #pragma unroll
    for (int m = 0; m < 4; m++)
      a[m] = *(const bf16x8*)&As[(kq * 128 + wr + m * 16 + fr) * 8];
    #pragma unroll
    for (int n = 0; n < 4; n++)
      b[n] = *(const bf16x8*)&Bs[(kq * 128 + wc + n * 16 + fr) * 8];
    #pragma unroll
    for (int m = 0; m < 4; m++)
      #pragma unroll
      for (int n = 0; n < 4; n++)
        acc[m][n] = __builtin_amdgcn_mfma_f32_16x16x32_bf16(a[m], b[n], acc[m][n], 0, 0, 0);
    __syncthreads();
  }

  // attn vector slices for this lane's 4 column-fragments (independent of wc)
  float as_[4], ad_[4];
  #pragma unroll
  for (int n = 0; n < 4; n++) {
    as_[n] = w_attn[n * 16 + fr];
    ad_[n] = w_attn[OD + n * 16 + fr];
  }
  const int crow = kq * 4;
  const int ccol = lane & 15;
  const int hh = (n0 + wc) >> 6;   // global head this wave's 64 cols form

  #pragma unroll
  for (int m = 0; m < 4; m++) {
    // bf16 z write
    #pragma unroll
    for (int n = 0; n < 4; n++) {
      int row = m0 + wr + m * 16 + crow;
      int col = n0 + wc + n * 16 + ccol;
      #pragma unroll
      for (int j = 0; j < 4; j++)
        if (row + j < NN) zb[(size_t)(row + j) * ZD + col] = f2b(acc[m][n][j]);
    }
    // fused scores: per-row dot over this wave's 64 cols, reduce across fr
    float sp[4] = {0.f, 0.f, 0.f, 0.f}, sd[4] = {0.f, 0.f, 0.f, 0.f};
    #pragma unroll
    for (int n = 0; n < 4; n++)
      #pragma unroll
      for (int j = 0; j < 4; j++) {
        sp[j] = fmaf(acc[m][n][j], as_[n], sp[j]);
        sd[j] = fmaf(acc[m][n][j], ad_[n], sd[j]);
      }
    #pragma unroll
    for (int o = 1; o < 16; o <<= 1)
      #pragma unroll
      for (int j = 0; j < 4; j++) {
        sp[j] += __shfl_xor(sp[j], o);
        sd[j] += __shfl_xor(sd[j], o);
      }
    if (fr == 0) {
      int row = m0 + wr + m * 16 + crow;
      #pragma unroll
      for (int j = 0; j < 4; j++)
        if (row + j < NN) {
          s_src[(size_t)(row + j) * NH + hh] = sp[j];
          s_dst[(size_t)(row + j) * NH + hh] = sd[j];
        }
    }
  }
}

// ---------- per-edge scores: e = lrelu(s_src[src] + s_dst[dst] + dep_emb@wfa) ----------
__global__ __launch_bounds__(256) void k_edge(const float* __restrict__ dep_emb,
    const int* __restrict__ src, const int* __restrict__ dst,
    const float* __restrict__ wfa, const float* __restrict__ s_src,
    const float* __restrict__ s_dst, float* __restrict__ e_out) {
  __shared__ float rows[64][FEAT_DIM + 4];
  __shared__ float wfa_s[FEAT_DIM * NH];
  const int t  = threadIdx.x;
  const int e0 = blockIdx.x * 64;
  *(float4*)&wfa_s[t * 4] = *(const float4*)&wfa[t * 4];
  const float4* g = (const float4*)(dep_emb + (size_t)e0 * FEAT_DIM);
  #pragma unroll
  for (int r = 0; r < 8; r++) {
    int idx = t + r * 256;
    float4 v = g[idx];
    *(float4*)&rows[idx >> 5][(idx & 31) * 4] = v;
  }
  __syncthreads();
  const int le = t >> 2, c = t & 3;
  float acc[NH];
  #pragma unroll
  for (int h = 0; h < NH; h++) acc[h] = 0.f;
  #pragma unroll
  for (int i = 0; i < 32; i += 4) {
    float4 v = *(float4*)&rows[le][c * 32 + i];
    const float* w0 = &wfa_s[(c * 32 + i) * NH];
    #pragma unroll
    for (int j = 0; j < 4; j++) {
      float x = (&v.x)[j];
      #pragma unroll
      for (int h = 0; h < NH; h++) acc[h] = fmaf(x, w0[j * NH + h], acc[h]);
    }
  }
  #pragma unroll
  for (int h = 0; h < NH; h++) {
    acc[h] += __shfl_xor(acc[h], 1);
    acc[h] += __shfl_xor(acc[h], 2);
  }
  int eid = e0 + le;
  int s = src[eid], dd = dst[eid];
  int h0 = c * 2;
  float v0 = acc[h0]     + s_src[s * NH + h0]     + s_dst[dd * NH + h0];
  float v1 = acc[h0 + 1] + s_src[s * NH + h0 + 1] + s_dst[dd * NH + h0 + 1];
  float2 r2;
  r2.x = v0 >= 0.f ? v0 : NEG * v0;
  r2.y = v1 >= 0.f ? v1 : NEG * v1;
  *(float2*)&e_out[(size_t)eid * NH + h0] = r2;
}

// ---------- segment softmax + weighted bf16-gather aggregate ----------
// 256 threads: thread t owns cols {2t, 2t+1}; head h = t>>5
#define CHUNK 256
__global__ __launch_bounds__(256) void k_agg(const float* __restrict__ e_sc,
    const int* __restrict__ src, const int* __restrict__ row_start,
    const unsigned short* __restrict__ zb, float* __restrict__ out) {
  const int n = blockIdx.x;
  const int start = row_start[n], end = row_start[n + 1];
  const int t = threadIdx.x;
  const int h = t >> 5;            // 32 threads per head
  const int g = t & 31;
  __shared__ float m_s[NH], den_s[NH];
  __shared__ float ex_s[CHUNK * NH];
  __shared__ int   src_s[CHUNK];

  // pass 1: per-head max + denom (32-lane group per head)
  {
    float mx = -INFINITY;
    for (int eid = start + g; eid < end; eid += 32)
      mx = fmaxf(mx, e_sc[(size_t)eid * NH + h]);
    #pragma unroll
    for (int o = 16; o > 0; o >>= 1) mx = fmaxf(mx, __shfl_xor(mx, o));
    float sm = 0.f;
    for (int eid = start + g; eid < end; eid += 32)
      sm += __expf(e_sc[(size_t)eid * NH + h] - mx);
    #pragma unroll
    for (int o = 16; o > 0; o >>= 1) sm += __shfl_xor(sm, o);
    if (g == 0) { m_s[h] = (end > start) ? mx : 0.f; den_s[h] = (end > start) ? sm : 0.f; }
  }
  __syncthreads();

  // pass 2: chunked exp staging + coalesced bf16 z-gather accumulate
  float acc0 = 0.f, acc1 = 0.f;
  for (int c0 = start; c0 < end; c0 += CHUNK) {
    int cn = min(CHUNK, end - c0);
    for (int idx = t; idx < cn * NH; idx += 256) {
      int i = idx >> 3, hh = idx & 7;
      ex_s[idx] = __expf(e_sc[(size_t)(c0 + i) * NH + hh] - m_s[hh]);
    }
    for (int idx = t; idx < cn; idx += 256) src_s[idx] = src[c0 + idx];
    __syncthreads();
    for (int i = 0; i < cn; i++) {
      float w = ex_s[i * NH + h];
      unsigned int u = *(const unsigned int*)(zb + (size_t)src_s[i] * ZD + t * 2);
      acc0 = fmaf(w, b2f((unsigned short)(u & 0xFFFF)), acc0);
      acc1 = fmaf(w, b2f((unsigned short)(u >> 16)), acc1);
    }
    __syncthreads();
  }
  float den = den_s[h];
  float inv = (den > 0.f) ? 1.f / den : 0.f;
  float2 r2; r2.x = acc0 * inv; r2.y = acc1 * inv;
  *(float2*)&out[(size_t)n * ZD + t * 2] = r2;
}

extern "C" void kernel_launch(void* const* d_in, const int* in_sizes, int n_in,
                              void* d_out, int out_size, void* d_ws, size_t ws_size,
                              hipStream_t stream) {
  const float* h      = (const float*)d_in[0];
  const float* dep    = (const float*)d_in[1];
  const int*   src    = (const int*)d_in[2];
  const int*   dst    = (const int*)d_in[3];
  const float* w_fc   = (const float*)d_in[4];
  const float* w_feat = (const float*)d_in[5];
  const float* w_attn = (const float*)d_in[6];
  float* out = (float*)d_out;

  char* ws = (char*)d_ws;
  size_t off = 0;
  auto alloc = [&](size_t bytes) { void* p = ws + off; off = (off + bytes + 63) & ~(size_t)63; return p; };
  float* s_src  = (float*)alloc((size_t)NN * NH * 4);
  float* s_dst  = (float*)alloc((size_t)NN * NH * 4);
  float* e_sc   = (float*)alloc((size_t)NE * NH * 4);
  float* wfa    = (float*)alloc(FEAT_DIM * NH * 4);
  int*   row_st = (int*)alloc((NN + 2) * 4);
  unsigned short* zb = (unsigned short*)alloc((size_t)NN * ZD * 2);
  unsigned short* hb = (unsigned short*)alloc((size_t)NPAD * IN_DIM * 2);
  unsigned short* wt = (unsigned short*)alloc((size_t)IN_DIM * ZD * 2);

  k_prep   <<<PREP_ALL, 256, 0, stream>>>(h, w_fc, w_feat, w_attn, dst, hb, wt, wfa, row_st);
  k_gemm_bf<<<dim3(NPAD / 128, ZD / 128), 256, 0, stream>>>(hb, wt, w_attn, zb, s_src, s_dst);
  k_edge   <<<NE / 64, 256, 0, stream>>>(dep, src, dst, wfa, s_src, s_dst, e_sc);
  k_agg    <<<NN, 256, 0, stream>>>(e_sc, src, row_st, zb, out);
}

// Round 4
// 125.625 us; speedup vs baseline: 1.8481x; 1.0251x over previous
//
#include <hip/hip_runtime.h>
#include <math.h>

#define NN 10000
#define NPAD 10112     // 79*128
#define NE 320000
#define IN_DIM 512
#define FEAT_DIM 128
#define OD 64
#define NH 8
#define ZD 512          // OD*NH
#define NEG 0.01f

typedef __attribute__((ext_vector_type(8))) __bf16 bf16x8;
typedef __attribute__((ext_vector_type(4))) float f32x4;

__device__ __forceinline__ unsigned short f2b(float f) {
  __bf16 b = (__bf16)f;
  return __builtin_bit_cast(unsigned short, b);
}
__device__ __forceinline__ float b2f(unsigned int u16) {
  unsigned int x = u16 << 16;
  return __builtin_bit_cast(float, x);
}

__device__ __forceinline__ void gload16(const void* g, void* l) {
  __builtin_amdgcn_global_load_lds((const __attribute__((address_space(1))) unsigned int*)g,
                                   (__attribute__((address_space(3))) unsigned int*)l, 16, 0, 0);
}

// ---------- fused prep: h->bf16 | w_fc transpose->bf16 | wfa fold | CSR rows ----------
#define PREP_H2B 2528
#define PREP_WT  (PREP_H2B + 256)
#define PREP_WFA (PREP_WT + 4)
#define PREP_ALL (PREP_WFA + 40)
__global__ __launch_bounds__(256) void k_prep(const float* __restrict__ h,
    const float* __restrict__ w_fc, const float* __restrict__ w_feat,
    const float* __restrict__ w_attn, const int* __restrict__ dst,
    unsigned short* __restrict__ hb, unsigned short* __restrict__ wt,
    float* __restrict__ wfa, int* __restrict__ row_start) {
  const int bid = blockIdx.x, t = threadIdx.x;
  if (bid < PREP_H2B) {
    size_t base = ((size_t)bid * 256 + t) * 8;
    int row = (int)(base >> 9);
    ushort4 o0, o1;
    if (row < NN) {
      float4 v0 = *(const float4*)(h + base);
      float4 v1 = *(const float4*)(h + base + 4);
      o0 = make_ushort4(f2b(v0.x), f2b(v0.y), f2b(v0.z), f2b(v0.w));
      o1 = make_ushort4(f2b(v1.x), f2b(v1.y), f2b(v1.z), f2b(v1.w));
    } else {
      o0 = make_ushort4(0, 0, 0, 0);
      o1 = make_ushort4(0, 0, 0, 0);
    }
    *(ushort4*)(hb + base) = o0;
    *(ushort4*)(hb + base + 4) = o1;
  } else if (bid < PREP_WT) {
    __shared__ float tile[32][33];
    const int b2 = bid - PREP_H2B;
    const int tx = (b2 & 15) * 32, ty = (b2 >> 4) * 32;
    const int r = t >> 3, c4 = (t & 7) * 4;
    float4 v = *(const float4*)(w_fc + (size_t)(ty + r) * ZD + tx + c4);
    tile[r][c4 + 0] = v.x; tile[r][c4 + 1] = v.y; tile[r][c4 + 2] = v.z; tile[r][c4 + 3] = v.w;
    __syncthreads();
    ushort4 o = make_ushort4(f2b(tile[c4 + 0][r]), f2b(tile[c4 + 1][r]),
                             f2b(tile[c4 + 2][r]), f2b(tile[c4 + 3][r]));
    *(ushort4*)(wt + (size_t)(tx + r) * IN_DIM + ty + c4) = o;
  } else if (bid < PREP_WFA) {
    int tid = (bid - PREP_WT) * 256 + t;
    if (tid < FEAT_DIM * NH) {
      int f = tid >> 3, hh = tid & 7;
      const float* wr = w_feat + (size_t)f * ZD + hh * OD;
      const float* a  = w_attn + 2 * OD;
      float s = 0.f;
      #pragma unroll 8
      for (int d = 0; d < OD; ++d) s += wr[d] * a[d];
      wfa[f * NH + hh] = s;
    }
  } else {
    int n = (bid - PREP_WFA) * 256 + t;
    if (n <= NN) {
      int lo = 0, hi = NE;
      while (lo < hi) { int mid = (lo + hi) >> 1; if (dst[mid] < n) lo = mid + 1; else hi = mid; }
      row_start[n] = lo;
    }
  }
}

// ---------- fused: [0,316) bf16-MFMA gemm (+score epilogue)  |  [316,5316) e_feat = dep@wfa ----------
#define GEMM_BLOCKS 316   // 79 * 4
__global__ __launch_bounds__(256) void k_fused(const unsigned short* __restrict__ A,
    const unsigned short* __restrict__ Bt, const float* __restrict__ w_attn,
    const float* __restrict__ dep_emb, const float* __restrict__ wfa,
    unsigned short* __restrict__ zb, float* __restrict__ s_src,
    float* __restrict__ s_dst, float* __restrict__ e_feat) {
  __shared__ __align__(16) char smem[40000];
  const int bid = blockIdx.x, t = threadIdx.x;

  if (bid < GEMM_BLOCKS) {
    // ---- GEMM role ----
    unsigned short* As = (unsigned short*)smem;            // 4*128*8 bf16 = 8 KB
    unsigned short* Bs = (unsigned short*)(smem + 8192);   // 8 KB
    const int m0 = (bid % 79) * 128;
    const int n0 = (bid / 79) * 128;
    const int lane = t & 63, wave = t >> 6;
    const int wr = (wave >> 1) * 64, wc = (wave & 1) * 64;
    const int fr = lane & 15, kq = lane >> 4;

    f32x4 acc[4][4] = {};

    const int idx0 = t, idx1 = t + 256;
    const unsigned short* ga0 = A + (size_t)(m0 + (idx0 & 127)) * IN_DIM + (idx0 >> 7) * 8;
    const unsigned short* ga1 = A + (size_t)(m0 + (idx1 & 127)) * IN_DIM + (idx1 >> 7) * 8;
    const unsigned short* gb0 = Bt + (size_t)(n0 + (idx0 & 127)) * IN_DIM + (idx0 >> 7) * 8;
    const unsigned short* gb1 = Bt + (size_t)(n0 + (idx1 & 127)) * IN_DIM + (idx1 >> 7) * 8;
    unsigned short* la0 = &As[idx0 * 8];
    unsigned short* la1 = &As[idx1 * 8];
    unsigned short* lb0 = &Bs[idx0 * 8];
    unsigned short* lb1 = &Bs[idx1 * 8];

    for (int k0 = 0; k0 < IN_DIM; k0 += 32) {
      gload16(ga0 + k0, la0);
      gload16(ga1 + k0, la1);
      gload16(gb0 + k0, lb0);
      gload16(gb1 + k0, lb1);
      __syncthreads();
      bf16x8 a[4], b[4];
      #pragma unroll
      for (int m = 0; m < 4; m++)
        a[m] = *(const bf16x8*)&As[(kq * 128 + wr + m * 16 + fr) * 8];
      #pragma unroll
      for (int n = 0; n < 4; n++)
        b[n] = *(const bf16x8*)&Bs[(kq * 128 + wc + n * 16 + fr) * 8];
      #pragma unroll
      for (int m = 0; m < 4; m++)
        #pragma unroll
        for (int n = 0; n < 4; n++)
          acc[m][n] = __builtin_amdgcn_mfma_f32_16x16x32_bf16(a[m], b[n], acc[m][n], 0, 0, 0);
      __syncthreads();
    }

    float as_[4], ad_[4];
    #pragma unroll
    for (int n = 0; n < 4; n++) {
      as_[n] = w_attn[n * 16 + fr];
      ad_[n] = w_attn[OD + n * 16 + fr];
    }
    const int crow = kq * 4;
    const int ccol = lane & 15;
    const int hh = (n0 + wc) >> 6;

    #pragma unroll
    for (int m = 0; m < 4; m++) {
      #pragma unroll
      for (int n = 0; n < 4; n++) {
        int row = m0 + wr + m * 16 + crow;
        int col = n0 + wc + n * 16 + ccol;
        #pragma unroll
        for (int j = 0; j < 4; j++)
          if (row + j < NN) zb[(size_t)(row + j) * ZD + col] = f2b(acc[m][n][j]);
      }
      float sp[4] = {0.f, 0.f, 0.f, 0.f}, sd[4] = {0.f, 0.f, 0.f, 0.f};
      #pragma unroll
      for (int n = 0; n < 4; n++)
        #pragma unroll
        for (int j = 0; j < 4; j++) {
          sp[j] = fmaf(acc[m][n][j], as_[n], sp[j]);
          sd[j] = fmaf(acc[m][n][j], ad_[n], sd[j]);
        }
      #pragma unroll
      for (int o = 1; o < 16; o <<= 1)
        #pragma unroll
        for (int j = 0; j < 4; j++) {
          sp[j] += __shfl_xor(sp[j], o);
          sd[j] += __shfl_xor(sd[j], o);
        }
      if (fr == 0) {
        int row = m0 + wr + m * 16 + crow;
        #pragma unroll
        for (int j = 0; j < 4; j++)
          if (row + j < NN) {
            s_src[(size_t)(row + j) * NH + hh] = sp[j];
            s_dst[(size_t)(row + j) * NH + hh] = sd[j];
          }
      }
    }
  } else {
    // ---- edge-feature role: e_feat[h][e] = dep_emb[e] . wfa[:,h] ----
    float* rows  = (float*)smem;                    // [64][132]
    float* wfa_s = (float*)(smem + 33792);          // [1024]
    float* e_tmp = (float*)(smem + 33792 + 4096);   // [8][66]
    const int e0 = (bid - GEMM_BLOCKS) * 64;

    *(float4*)&wfa_s[t * 4] = *(const float4*)&wfa[t * 4];
    const float4* g = (const float4*)(dep_emb + (size_t)e0 * FEAT_DIM);
    #pragma unroll
    for (int r = 0; r < 8; r++) {
      int idx = t + r * 256;
      float4 v = g[idx];
      *(float4*)&rows[(idx >> 5) * 132 + (idx & 31) * 4] = v;
    }
    __syncthreads();
    const int le = t >> 2, c = t & 3;
    float acc[NH];
    #pragma unroll
    for (int h = 0; h < NH; h++) acc[h] = 0.f;
    #pragma unroll
    for (int i = 0; i < 32; i += 4) {
      float4 v = *(float4*)&rows[le * 132 + c * 32 + i];
      const float* w0 = &wfa_s[(c * 32 + i) * NH];
      #pragma unroll
      for (int j = 0; j < 4; j++) {
        float x = (&v.x)[j];
        #pragma unroll
        for (int h = 0; h < NH; h++) acc[h] = fmaf(x, w0[j * NH + h], acc[h]);
      }
    }
    #pragma unroll
    for (int h = 0; h < NH; h++) {
      acc[h] += __shfl_xor(acc[h], 1);
      acc[h] += __shfl_xor(acc[h], 2);
    }
    int h0 = c * 2;
    e_tmp[h0 * 66 + le]       = acc[h0];
    e_tmp[(h0 + 1) * 66 + le] = acc[h0 + 1];
    __syncthreads();
    #pragma unroll
    for (int r = 0; r < 2; r++) {
      int idx = t + r * 256;
      int h = idx >> 6, el = idx & 63;
      e_feat[(size_t)h * NE + e0 + el] = e_tmp[h * 66 + el];
    }
  }
}

// ---------- per-node: score assembly + online segment softmax + bf16 gather aggregate ----------
#define CH 128
__global__ __launch_bounds__(256) void k_agg(const float* __restrict__ e_feat,
    const int* __restrict__ src, const int* __restrict__ row_start,
    const float* __restrict__ s_src, const float* __restrict__ s_dst,
    const unsigned short* __restrict__ zb, float* __restrict__ out) {
  const int n = blockIdx.x;
  const int start = row_start[n], end = row_start[n + 1];
  const int t = threadIdx.x;
  const int h = t >> 5, g = t & 31;
  __shared__ int   src_s[CH];
  __shared__ float e_s[NH * CH];

  float m = -INFINITY, den = 0.f;
  float a0e = 0.f, a1e = 0.f, a0o = 0.f, a1o = 0.f;
  const unsigned short* zcol = zb + t * 2;

  for (int c0 = start; c0 < end; c0 += CH) {
    const int cn = min(CH, end - c0);
    // stage src ids
    for (int i = t; i < cn; i += 256) src_s[i] = src[c0 + i];
    // stage full edge scores e = lrelu(e_feat + s_src[src] + s_dst[n])
    #pragma unroll
    for (int rep = 0; rep < NH * CH / 256; rep++) {
      int idx = t + rep * 256;
      int hh = idx >> 7, i = idx & (CH - 1);
      if (i < cn) {
        int sid = src[c0 + i];
        float e = e_feat[(size_t)hh * NE + c0 + i] + s_src[(size_t)sid * NH + hh]
                + s_dst[(size_t)n * NH + hh];
        e_s[hh * CH + i] = e >= 0.f ? e : NEG * e;
      }
    }
    __syncthreads();
    // per-head chunk max (32-lane group per head)
    float mc = -INFINITY;
    for (int i = g; i < cn; i += 32) mc = fmaxf(mc, e_s[h * CH + i]);
    #pragma unroll
    for (int o = 16; o > 0; o >>= 1) mc = fmaxf(mc, __shfl_xor(mc, o, 32));
    float mn = fmaxf(m, mc);
    // exp writeback + chunk denom
    float sc = 0.f;
    for (int i = g; i < cn; i += 32) {
      float ex = __expf(e_s[h * CH + i] - mn);
      e_s[h * CH + i] = ex;
      sc += ex;
    }
    #pragma unroll
    for (int o = 16; o > 0; o >>= 1) sc += __shfl_xor(sc, o, 32);
    float rs = __expf(m - mn);
    den = den * rs + sc;
    a0e *= rs; a1e *= rs; a0o *= rs; a1o *= rs;
    m = mn;
    // gather-accumulate, 8-deep ILP
    int i = 0;
    for (; i + 8 <= cn; i += 8) {
      int r0 = src_s[i], r1 = src_s[i+1], r2 = src_s[i+2], r3 = src_s[i+3];
      int r4 = src_s[i+4], r5 = src_s[i+5], r6 = src_s[i+6], r7 = src_s[i+7];
      float w0 = e_s[h*CH+i],   w1 = e_s[h*CH+i+1], w2 = e_s[h*CH+i+2], w3 = e_s[h*CH+i+3];
      float w4 = e_s[h*CH+i+4], w5 = e_s[h*CH+i+5], w6 = e_s[h*CH+i+6], w7 = e_s[h*CH+i+7];
      unsigned u0 = *(const unsigned*)(zcol + ((size_t)r0 << 9));
      unsigned u1 = *(const unsigned*)(zcol + ((size_t)r1 << 9));
      unsigned u2 = *(const unsigned*)(zcol + ((size_t)r2 << 9));
      unsigned u3 = *(const unsigned*)(zcol + ((size_t)r3 << 9));
      unsigned u4 = *(const unsigned*)(zcol + ((size_t)r4 << 9));
      unsigned u5 = *(const unsigned*)(zcol + ((size_t)r5 << 9));
      unsigned u6 = *(const unsigned*)(zcol + ((size_t)r6 << 9));
      unsigned u7 = *(const unsigned*)(zcol + ((size_t)r7 << 9));
      a0e = fmaf(w0, b2f(u0 & 0xFFFF), a0e); a1e = fmaf(w0, b2f(u0 >> 16), a1e);
      a0o = fmaf(w1, b2f(u1 & 0xFFFF), a0o); a1o = fmaf(w1, b2f(u1 >> 16), a1o);
      a0e = fmaf(w2, b2f(u2 & 0xFFFF), a0e); a1e = fmaf(w2, b2f(u2 >> 16), a1e);
      a0o = fmaf(w3, b2f(u3 & 0xFFFF), a0o); a1o = fmaf(w3, b2f(u3 >> 16), a1o);
      a0e = fmaf(w4, b2f(u4 & 0xFFFF), a0e); a1e = fmaf(w4, b2f(u4 >> 16), a1e);
      a0o = fmaf(w5, b2f(u5 & 0xFFFF), a0o); a1o = fmaf(w5, b2f(u5 >> 16), a1o);
      a0e = fmaf(w6, b2f(u6 & 0xFFFF), a0e); a1e = fmaf(w6, b2f(u6 >> 16), a1e);
      a0o = fmaf(w7, b2f(u7 & 0xFFFF), a0o); a1o = fmaf(w7, b2f(u7 >> 16), a1o);
    }
    for (; i < cn; i++) {
      int r = src_s[i];
      float w = e_s[h * CH + i];
      unsigned u = *(const unsigned*)(zcol + ((size_t)r << 9));
      a0e = fmaf(w, b2f(u & 0xFFFF), a0e);
      a1e = fmaf(w, b2f(u >> 16), a1e);
    }
    __syncthreads();
  }
  float den_inv = den > 0.f ? 1.f / den : 0.f;
  float2 r2;
  r2.x = (a0e + a0o) * den_inv;
  r2.y = (a1e + a1o) * den_inv;
  *(float2*)&out[(size_t)n * ZD + t * 2] = r2;
}

extern "C" void kernel_launch(void* const* d_in, const int* in_sizes, int n_in,
                              void* d_out, int out_size, void* d_ws, size_t ws_size,
                              hipStream_t stream) {
  const float* h      = (const float*)d_in[0];
  const float* dep    = (const float*)d_in[1];
  const int*   src    = (const int*)d_in[2];
  const int*   dst    = (const int*)d_in[3];
  const float* w_fc   = (const float*)d_in[4];
  const float* w_feat = (const float*)d_in[5];
  const float* w_attn = (const float*)d_in[6];
  float* out = (float*)d_out;

  char* ws = (char*)d_ws;
  size_t off = 0;
  auto alloc = [&](size_t bytes) { void* p = ws + off; off = (off + bytes + 63) & ~(size_t)63; return p; };
  float* s_src  = (float*)alloc((size_t)NN * NH * 4);
  float* s_dst  = (float*)alloc((size_t)NN * NH * 4);
  float* e_feat = (float*)alloc((size_t)NE * NH * 4);   // head-major [NH][NE]
  float* wfa    = (float*)alloc(FEAT_DIM * NH * 4);
  int*   row_st = (int*)alloc((NN + 2) * 4);
  unsigned short* zb = (unsigned short*)alloc((size_t)NN * ZD * 2);
  unsigned short* hb = (unsigned short*)alloc((size_t)NPAD * IN_DIM * 2);
  unsigned short* wt = (unsigned short*)alloc((size_t)IN_DIM * ZD * 2);

  k_prep <<<PREP_ALL, 256, 0, stream>>>(h, w_fc, w_feat, w_attn, dst, hb, wt, wfa, row_st);
  k_fused<<<GEMM_BLOCKS + NE / 64, 256, 0, stream>>>(hb, wt, w_attn, dep, wfa,
                                                     zb, s_src, s_dst, e_feat);
  k_agg  <<<NN, 256, 0, stream>>>(e_feat, src, row_st, s_src, s_dst, zb, out);
}

// Round 5
// 113.641 us; speedup vs baseline: 2.0430x; 1.1055x over previous
//
#include <hip/hip_runtime.h>
#include <math.h>

#define NN 10000
#define NPAD 10112     // 79*128
#define NE 320000
#define IN_DIM 512
#define FEAT_DIM 128
#define OD 64
#define NH 8
#define ZD 512          // OD*NH
#define NEG 0.01f

typedef __attribute__((ext_vector_type(8))) __bf16 bf16x8;
typedef __attribute__((ext_vector_type(4))) float f32x4;
typedef __attribute__((ext_vector_type(8))) unsigned short u16x8;

__device__ __forceinline__ unsigned short f2b(float f) {
  __bf16 b = (__bf16)f;
  return __builtin_bit_cast(unsigned short, b);
}
__device__ __forceinline__ float b2f(unsigned int u16) {
  unsigned int x = u16 << 16;
  return __builtin_bit_cast(float, x);
}

__device__ __forceinline__ void gload16(const void* g, void* l) {
  __builtin_amdgcn_global_load_lds((const __attribute__((address_space(1))) unsigned int*)g,
                                   (__attribute__((address_space(3))) unsigned int*)l, 16, 0, 0);
}

// ---------- fused prep: h->bf16 | w_fc transpose->bf16 | wfa fold | CSR rows ----------
#define PREP_H2B 2528
#define PREP_WT  (PREP_H2B + 256)
#define PREP_WFA (PREP_WT + 4)
#define PREP_ALL (PREP_WFA + 40)
__global__ __launch_bounds__(256) void k_prep(const float* __restrict__ h,
    const float* __restrict__ w_fc, const float* __restrict__ w_feat,
    const float* __restrict__ w_attn, const int* __restrict__ dst,
    unsigned short* __restrict__ hb, unsigned short* __restrict__ wt,
    float* __restrict__ wfa, int* __restrict__ row_start) {
  const int bid = blockIdx.x, t = threadIdx.x;
  if (bid < PREP_H2B) {
    size_t base = ((size_t)bid * 256 + t) * 8;
    int row = (int)(base >> 9);
    ushort4 o0, o1;
    if (row < NN) {
      float4 v0 = *(const float4*)(h + base);
      float4 v1 = *(const float4*)(h + base + 4);
      o0 = make_ushort4(f2b(v0.x), f2b(v0.y), f2b(v0.z), f2b(v0.w));
      o1 = make_ushort4(f2b(v1.x), f2b(v1.y), f2b(v1.z), f2b(v1.w));
    } else {
      o0 = make_ushort4(0, 0, 0, 0);
      o1 = make_ushort4(0, 0, 0, 0);
    }
    *(ushort4*)(hb + base) = o0;
    *(ushort4*)(hb + base + 4) = o1;
  } else if (bid < PREP_WT) {
    __shared__ float tile[32][33];
    const int b2 = bid - PREP_H2B;
    const int tx = (b2 & 15) * 32, ty = (b2 >> 4) * 32;
    const int r = t >> 3, c4 = (t & 7) * 4;
    float4 v = *(const float4*)(w_fc + (size_t)(ty + r) * ZD + tx + c4);
    tile[r][c4 + 0] = v.x; tile[r][c4 + 1] = v.y; tile[r][c4 + 2] = v.z; tile[r][c4 + 3] = v.w;
    __syncthreads();
    ushort4 o = make_ushort4(f2b(tile[c4 + 0][r]), f2b(tile[c4 + 1][r]),
                             f2b(tile[c4 + 2][r]), f2b(tile[c4 + 3][r]));
    *(ushort4*)(wt + (size_t)(tx + r) * IN_DIM + ty + c4) = o;
  } else if (bid < PREP_WFA) {
    int tid = (bid - PREP_WT) * 256 + t;
    if (tid < FEAT_DIM * NH) {
      int f = tid >> 3, hh = tid & 7;
      const float* wr = w_feat + (size_t)f * ZD + hh * OD;
      const float* a  = w_attn + 2 * OD;
      float s = 0.f;
      #pragma unroll 8
      for (int d = 0; d < OD; ++d) s += wr[d] * a[d];
      wfa[f * NH + hh] = s;
    }
  } else {
    int n = (bid - PREP_WFA) * 256 + t;
    if (n <= NN) {
      int lo = 0, hi = NE;
      while (lo < hi) { int mid = (lo + hi) >> 1; if (dst[mid] < n) lo = mid + 1; else hi = mid; }
      row_start[n] = lo;
    }
  }
}

// ---------- fused: [0,316) bf16-MFMA gemm (+score epilogue)  |  [316,5316) e_feat = dep@wfa ----------
#define GEMM_BLOCKS 316   // 79 * 4
__global__ __launch_bounds__(256) void k_fused(const unsigned short* __restrict__ A,
    const unsigned short* __restrict__ Bt, const float* __restrict__ w_attn,
    const float* __restrict__ dep_emb, const float* __restrict__ wfa,
    unsigned short* __restrict__ zb, float* __restrict__ s_src,
    float* __restrict__ s_dst, float* __restrict__ e_feat) {
  __shared__ __align__(16) char smem[38400];
  const int bid = blockIdx.x, t = threadIdx.x;

  if (bid < GEMM_BLOCKS) {
    // ---- GEMM role ----
    unsigned short* As = (unsigned short*)smem;            // 8 KB
    unsigned short* Bs = (unsigned short*)(smem + 8192);   // 8 KB
    const int m0 = (bid % 79) * 128;
    const int n0 = (bid / 79) * 128;
    const int lane = t & 63, wave = t >> 6;
    const int wr = (wave >> 1) * 64, wc = (wave & 1) * 64;
    const int fr = lane & 15, kq = lane >> 4;

    f32x4 acc[4][4] = {};

    const int idx0 = t, idx1 = t + 256;
    const unsigned short* ga0 = A + (size_t)(m0 + (idx0 & 127)) * IN_DIM + (idx0 >> 7) * 8;
    const unsigned short* ga1 = A + (size_t)(m0 + (idx1 & 127)) * IN_DIM + (idx1 >> 7) * 8;
    const unsigned short* gb0 = Bt + (size_t)(n0 + (idx0 & 127)) * IN_DIM + (idx0 >> 7) * 8;
    const unsigned short* gb1 = Bt + (size_t)(n0 + (idx1 & 127)) * IN_DIM + (idx1 >> 7) * 8;
    unsigned short* la0 = &As[idx0 * 8];
    unsigned short* la1 = &As[idx1 * 8];
    unsigned short* lb0 = &Bs[idx0 * 8];
    unsigned short* lb1 = &Bs[idx1 * 8];

    for (int k0 = 0; k0 < IN_DIM; k0 += 32) {
      gload16(ga0 + k0, la0);
      gload16(ga1 + k0, la1);
      gload16(gb0 + k0, lb0);
      gload16(gb1 + k0, lb1);
      __syncthreads();
      bf16x8 a[4], b[4];
      #pragma unroll
      for (int m = 0; m < 4; m++)
        a[m] = *(const bf16x8*)&As[(kq * 128 + wr + m * 16 + fr) * 8];
      #pragma unroll
      for (int n = 0; n < 4; n++)
        b[n] = *(const bf16x8*)&Bs[(kq * 128 + wc + n * 16 + fr) * 8];
      #pragma unroll
      for (int m = 0; m < 4; m++)
        #pragma unroll
        for (int n = 0; n < 4; n++)
          acc[m][n] = __builtin_amdgcn_mfma_f32_16x16x32_bf16(a[m], b[n], acc[m][n], 0, 0, 0);
      __syncthreads();
    }

    float as_[4], ad_[4];
    #pragma unroll
    for (int n = 0; n < 4; n++) {
      as_[n] = w_attn[n * 16 + fr];
      ad_[n] = w_attn[OD + n * 16 + fr];
    }
    const int crow = kq * 4;
    const int ccol = lane & 15;
    const int hh = (n0 + wc) >> 6;

    #pragma unroll
    for (int m = 0; m < 4; m++) {
      #pragma unroll
      for (int n = 0; n < 4; n++) {
        int row = m0 + wr + m * 16 + crow;
        int col = n0 + wc + n * 16 + ccol;
        #pragma unroll
        for (int j = 0; j < 4; j++)
          if (row + j < NN) zb[(size_t)(row + j) * ZD + col] = f2b(acc[m][n][j]);
      }
      float sp[4] = {0.f, 0.f, 0.f, 0.f}, sd[4] = {0.f, 0.f, 0.f, 0.f};
      #pragma unroll
      for (int n = 0; n < 4; n++)
        #pragma unroll
        for (int j = 0; j < 4; j++) {
          sp[j] = fmaf(acc[m][n][j], as_[n], sp[j]);
          sd[j] = fmaf(acc[m][n][j], ad_[n], sd[j]);
        }
      #pragma unroll
      for (int o = 1; o < 16; o <<= 1)
        #pragma unroll
        for (int j = 0; j < 4; j++) {
          sp[j] += __shfl_xor(sp[j], o);
          sd[j] += __shfl_xor(sd[j], o);
        }
      if (fr == 0) {
        int row = m0 + wr + m * 16 + crow;
        #pragma unroll
        for (int j = 0; j < 4; j++)
          if (row + j < NN) {
            s_src[(size_t)(row + j) * NH + hh] = sp[j];
            s_dst[(size_t)(row + j) * NH + hh] = sd[j];
          }
      }
    }
  } else {
    // ---- edge-feature role: e_feat[e][h] = dep_emb[e] . wfa[:,h]  (edge-major) ----
    float* rows  = (float*)smem;                    // [64][132]
    float* wfa_s = (float*)(smem + 33792);          // [1024]
    const int e0 = (bid - GEMM_BLOCKS) * 64;

    *(float4*)&wfa_s[t * 4] = *(const float4*)&wfa[t * 4];
    const float4* g = (const float4*)(dep_emb + (size_t)e0 * FEAT_DIM);
    #pragma unroll
    for (int r = 0; r < 8; r++) {
      int idx = t + r * 256;
      float4 v = g[idx];
      *(float4*)&rows[(idx >> 5) * 132 + (idx & 31) * 4] = v;
    }
    __syncthreads();
    const int le = t >> 2, c = t & 3;
    float acc[NH];
    #pragma unroll
    for (int h = 0; h < NH; h++) acc[h] = 0.f;
    #pragma unroll
    for (int i = 0; i < 32; i += 4) {
      float4 v = *(float4*)&rows[le * 132 + c * 32 + i];
      const float* w0 = &wfa_s[(c * 32 + i) * NH];
      #pragma unroll
      for (int j = 0; j < 4; j++) {
        float x = (&v.x)[j];
        #pragma unroll
        for (int h = 0; h < NH; h++) acc[h] = fmaf(x, w0[j * NH + h], acc[h]);
      }
    }
    #pragma unroll
    for (int h = 0; h < NH; h++) {
      acc[h] += __shfl_xor(acc[h], 1);
      acc[h] += __shfl_xor(acc[h], 2);
    }
    int h0 = c * 2;
    float2 r2; r2.x = acc[h0]; r2.y = acc[h0 + 1];
    *(float2*)&e_feat[(size_t)(e0 + le) * NH + h0] = r2;
  }
}

// ---------- wave-per-node: score + online segment softmax + ushort8 gather aggregate ----------
#define CH2 64
__global__ __launch_bounds__(256) void k_agg(const float* __restrict__ ef,
    const int* __restrict__ src, const int* __restrict__ row_start,
    const float* __restrict__ s_src, const float* __restrict__ s_dst,
    const unsigned short* __restrict__ zb, float* __restrict__ out) {
  __shared__ float els[4 * CH2 * NH];   // per-wave exp'd scores [edge][head]
  __shared__ int   src_s[4 * CH2];
  const int t = threadIdx.x;
  const int w = t >> 6, l = t & 63;
  const int n = blockIdx.x * 4 + w;
  const int es = l >> 3;        // edge slot (score phase) == head hc (gather phase)
  const int hs = l & 7;         // head (score phase)
  const int hc = l >> 3;        // head owning cols [8l, 8l+8)
  float* myels = els + w * (CH2 * NH);
  int*   mysrc = src_s + w * CH2;

  const int start = row_start[n], end = row_start[n + 1];
  const float sdn = s_dst[(size_t)n * NH + hs];
  float m = -INFINITY, den = 0.f;
  float acc_e[8] = {0.f,0.f,0.f,0.f,0.f,0.f,0.f,0.f};
  float acc_o[8] = {0.f,0.f,0.f,0.f,0.f,0.f,0.f,0.f};
  const unsigned short* zcol = zb + l * 8;

  for (int c0 = start; c0 < end; c0 += CH2) {
    const int cn = min(CH2, end - c0);
    if (l < cn) mysrc[l] = src[c0 + l];
    // --- score phase: lane = (edge es, head hs) ---
    float e_r[CH2 / 8];
    float mchunk = -INFINITY;
    #pragma unroll
    for (int p = 0; p < CH2 / 8; p++) {
      int i = p * 8 + es;
      float e = -INFINITY;
      if (i < cn) {
        int sid = mysrc[i];
        e = ef[(size_t)(c0 + i) * NH + hs] + s_src[(size_t)sid * NH + hs] + sdn;
        e = e >= 0.f ? e : NEG * e;
      }
      e_r[p] = e;
      mchunk = fmaxf(mchunk, e);
    }
    mchunk = fmaxf(mchunk, __shfl_xor(mchunk, 8));
    mchunk = fmaxf(mchunk, __shfl_xor(mchunk, 16));
    mchunk = fmaxf(mchunk, __shfl_xor(mchunk, 32));
    float mn = fmaxf(m, mchunk);
    float dc = 0.f;
    #pragma unroll
    for (int p = 0; p < CH2 / 8; p++) {
      float ex = __expf(e_r[p] - mn);          // exp(-inf - mn) = 0 for invalid slots
      dc += ex;
      myels[(p * 8 + es) * NH + hs] = ex;
    }
    dc += __shfl_xor(dc, 8);
    dc += __shfl_xor(dc, 16);
    dc += __shfl_xor(dc, 32);
    float rs = __expf(m - mn);
    den = den * rs + dc;
    m = mn;
    // --- gather phase: lane = cols [8l,8l+8), head hc ---
    float rs_c = __shfl(rs, hc);
    #pragma unroll
    for (int j = 0; j < 8; j++) { acc_e[j] *= rs_c; acc_o[j] *= rs_c; }
    int i = 0;
    for (; i + 2 <= cn; i += 2) {
      int s0 = mysrc[i], s1 = mysrc[i + 1];
      float w0 = myels[i * NH + hc];
      float w1 = myels[(i + 1) * NH + hc];
      u16x8 u0 = *(const u16x8*)(zcol + ((size_t)s0 << 9));
      u16x8 u1 = *(const u16x8*)(zcol + ((size_t)s1 << 9));
      #pragma unroll
      for (int j = 0; j < 8; j++) acc_e[j] = fmaf(w0, b2f(u0[j]), acc_e[j]);
      #pragma unroll
      for (int j = 0; j < 8; j++) acc_o[j] = fmaf(w1, b2f(u1[j]), acc_o[j]);
    }
    if (i < cn) {
      int s0 = mysrc[i];
      float w0 = myels[i * NH + hc];
      u16x8 u0 = *(const u16x8*)(zcol + ((size_t)s0 << 9));
      #pragma unroll
      for (int j = 0; j < 8; j++) acc_e[j] = fmaf(w0, b2f(u0[j]), acc_e[j]);
    }
  }
  float den_c = __shfl(den, hc);
  float inv = den_c > 0.f ? 1.f / den_c : 0.f;
  float4 o0, o1;
  o0.x = (acc_e[0] + acc_o[0]) * inv; o0.y = (acc_e[1] + acc_o[1]) * inv;
  o0.z = (acc_e[2] + acc_o[2]) * inv; o0.w = (acc_e[3] + acc_o[3]) * inv;
  o1.x = (acc_e[4] + acc_o[4]) * inv; o1.y = (acc_e[5] + acc_o[5]) * inv;
  o1.z = (acc_e[6] + acc_o[6]) * inv; o1.w = (acc_e[7] + acc_o[7]) * inv;
  float* orow = out + (size_t)n * ZD + l * 8;
  *(float4*)orow = o0;
  *(float4*)(orow + 4) = o1;
}

extern "C" void kernel_launch(void* const* d_in, const int* in_sizes, int n_in,
                              void* d_out, int out_size, void* d_ws, size_t ws_size,
                              hipStream_t stream) {
  const float* h      = (const float*)d_in[0];
  const float* dep    = (const float*)d_in[1];
  const int*   src    = (const int*)d_in[2];
  const int*   dst    = (const int*)d_in[3];
  const float* w_fc   = (const float*)d_in[4];
  const float* w_feat = (const float*)d_in[5];
  const float* w_attn = (const float*)d_in[6];
  float* out = (float*)d_out;

  char* ws = (char*)d_ws;
  size_t off = 0;
  auto alloc = [&](size_t bytes) { void* p = ws + off; off = (off + bytes + 63) & ~(size_t)63; return p; };
  float* s_src  = (float*)alloc((size_t)NN * NH * 4);
  float* s_dst  = (float*)alloc((size_t)NN * NH * 4);
  float* e_feat = (float*)alloc((size_t)NE * NH * 4);   // edge-major [NE][NH]
  float* wfa    = (float*)alloc(FEAT_DIM * NH * 4);
  int*   row_st = (int*)alloc((NN + 2) * 4);
  unsigned short* zb = (unsigned short*)alloc((size_t)NN * ZD * 2);
  unsigned short* hb = (unsigned short*)alloc((size_t)NPAD * IN_DIM * 2);
  unsigned short* wt = (unsigned short*)alloc((size_t)IN_DIM * ZD * 2);

  k_prep <<<PREP_ALL, 256, 0, stream>>>(h, w_fc, w_feat, w_attn, dst, hb, wt, wfa, row_st);
  k_fused<<<GEMM_BLOCKS + NE / 64, 256, 0, stream>>>(hb, wt, w_attn, dep, wfa,
                                                     zb, s_src, s_dst, e_feat);
  k_agg  <<<NN / 4, 256, 0, stream>>>(e_feat, src, row_st, s_src, s_dst, zb, out);
}